// Round 5
// baseline (131.826 us; speedup 1.0000x reference)
//
#include <hip/hip_runtime.h>

// DCNv1 forward on MI355X, bf16 MFMA, round 8: 4-way K-split, 32-wo blocks, 2x16KB
// double-buffered B staging, 3 blocks/CU. B=8,C=128,H=W=64,O=128,3x3,pad=1.
//
// prep_kernel: blocks 0..511: x[B][C][H][W] f32 -> xt[B][H][W][C] bf16
//              blocks 512..583: wgt -> wpk, frag = ((tap*2+nh)*4+c0q)*4+ntl (16KB phase blocks)
// dcn_mfma_kernel: grid 1024 = (b, ho, wo-half), XCD-swizzled (1 b-plane per XCD).
//   512 thr = 8 waves = 2 mt (16-wo) x 4 kgrp (c0q). Each wave: 16wo x 128o x K32/tap.
//   18 phases (tap, nt-half): stage next 16KB B block into alternate buffer, blend A
//   (tap start), 4 ds_read_b128 + 4 MFMA, one barrier. A corners prefetched a full
//   tap ahead (~2 phases). No A-gather duplication vs round 7; B staging volume 2x
//   (L2-hot). LDS 36.4KB -> 3 blocks/CU (24 waves) with __launch_bounds__(512,6).
//   Epilogue: 2-round LDS K-reduction (kgrp 1,3 -> 0,2 -> 0) + direct float4 stores.

#define BB 8
#define CC 128
#define HH 64
#define WW 64
#define OO 128
#define KTAPS 9

typedef __attribute__((ext_vector_type(8))) short bf16x8;
typedef __attribute__((ext_vector_type(4))) float f32x4;

__device__ __forceinline__ unsigned short f2bf(float f) {
    unsigned u = __float_as_uint(f);
    u += 0x7FFFu + ((u >> 16) & 1u);   // RNE
    return (unsigned short)(u >> 16);
}
#if __has_builtin(__builtin_amdgcn_cvt_pk_bf16_f32)
typedef __attribute__((ext_vector_type(2))) __bf16 bf16x2_t;
__device__ __forceinline__ unsigned pack2bf(float lo, float hi) {
    bf16x2_t v = __builtin_amdgcn_cvt_pk_bf16_f32(lo, hi);
    unsigned r;
    __builtin_memcpy(&r, &v, 4);
    return r;
}
#else
__device__ __forceinline__ unsigned pack2bf(float lo, float hi) {
    return (unsigned)f2bf(lo) | ((unsigned)f2bf(hi) << 16);
}
#endif
__device__ __forceinline__ float bflo(unsigned p) { return __uint_as_float(p << 16); }
__device__ __forceinline__ float bfhi(unsigned p) { return __uint_as_float(p & 0xFFFF0000u); }

// async global->LDS 16B/lane copy; pointers laundered through uintptr_t.
__device__ __forceinline__ void gload_lds16(const void* g, void* l) {
#if __has_builtin(__builtin_amdgcn_global_load_lds)
    auto* lp = reinterpret_cast<__attribute__((address_space(3))) unsigned*>(
        reinterpret_cast<uintptr_t>(l));
    auto* gp = reinterpret_cast<const __attribute__((address_space(1))) unsigned*>(
        reinterpret_cast<uintptr_t>(g));
    __builtin_amdgcn_global_load_lds(gp, lp, 16, 0, 0);
#else
    const int lane = threadIdx.x & 63;
    *reinterpret_cast<uint4*>(reinterpret_cast<char*>(l) + lane * 16) =
        *reinterpret_cast<const uint4*>(reinterpret_cast<const char*>(g) + lane * 16);
#endif
}

// ---------------- prep: transpose x + pack weights (one launch) ----------------
__global__ __launch_bounds__(256)
void prep_kernel(const float* __restrict__ x, const float* __restrict__ wgt,
                 unsigned short* __restrict__ xt, unsigned short* __restrict__ wpk) {
    const int t = threadIdx.x;
    if (blockIdx.x < 512) {
        // ---- x[B][C][H][W] f32 -> xt[B][H][W][C] bf16 ----
        __shared__ float tile[WW * 132];
        const int b = blockIdx.x >> 6;
        const int h = blockIdx.x & 63;
        const float* src = x + ((size_t)b * CC * HH + h) * WW;
        {
            const int wq = t & 15;
            const int cb = t >> 4;
#pragma unroll
            for (int it = 0; it < 8; ++it) {
                const int c = it * 16 + cb;
                const float4 v = *reinterpret_cast<const float4*>(src + (size_t)c * (HH * WW) + wq * 4);
                tile[(wq * 4 + 0) * 132 + c] = v.x;
                tile[(wq * 4 + 1) * 132 + c] = v.y;
                tile[(wq * 4 + 2) * 132 + c] = v.z;
                tile[(wq * 4 + 3) * 132 + c] = v.w;
            }
        }
        __syncthreads();
        unsigned short* dst = xt + ((size_t)b * HH + h) * WW * CC;
        {
            const int cg = t & 15;
            const int wb = t >> 4;
#pragma unroll
            for (int it = 0; it < 4; ++it) {
                const int w = it * 16 + wb;
                const float* tp = &tile[w * 132 + cg * 8];
                uint4 p;
                p.x = pack2bf(tp[0], tp[1]);
                p.y = pack2bf(tp[2], tp[3]);
                p.z = pack2bf(tp[4], tp[5]);
                p.w = pack2bf(tp[6], tp[7]);
                *reinterpret_cast<uint4*>(&dst[(size_t)w * CC + cg * 8]) = p;
            }
        }
    } else {
        // ---- wgt[O][C][3][3] f32 -> wpk phase-blocked bf16 fragments ----
        // frag = ((tap*2+nh)*4 + c0q)*4 + ntl ; o = (nh*4+ntl)*16 + (lane&15),
        // c = c0q*32 + (lane>>4)*8
        const int id   = (blockIdx.x - 512) * 256 + t;   // 0..18431
        const int lane = id & 63;
        const int frag = id >> 6;                        // 0..287
        const int ntl  = frag & 3;
        const int c0q  = (frag >> 2) & 3;
        const int nh   = (frag >> 4) & 1;
        const int tap  = frag >> 5;
        const int o    = ((nh << 2) + ntl) * 16 + (lane & 15);
        const int c    = (c0q << 5) + ((lane >> 4) << 3);
        const float* s = wgt + ((size_t)o * CC + c) * KTAPS + tap;
        unsigned u[4];
#pragma unroll
        for (int j = 0; j < 4; ++j)
            u[j] = pack2bf(s[(2 * j) * KTAPS], s[(2 * j + 1) * KTAPS]);
        *reinterpret_cast<uint4*>(wpk + (size_t)frag * 512 + lane * 8) =
            make_uint4(u[0], u[1], u[2], u[3]);
    }
}

// decode one sampling record -> 4 corner byte-offsets + 4 bilinear weights.
__device__ __forceinline__ void decode_tap(const float2* __restrict__ sLL,
                                           const short2* __restrict__ sYX,
                                           int rec, int extra,
                                           unsigned& o00, unsigned& o01,
                                           unsigned& o10, unsigned& o11,
                                           float& w00, float& w01,
                                           float& w10, float& w11) {
    const float2 ll = sLL[rec];
    const short2 yx = sYX[rec];
    const int y0 = yx.x, x0 = yx.y;
    const int y1 = y0 + 1, x1 = x0 + 1;
    const float ly = ll.x, lx = ll.y;
    const bool vy0 = ((unsigned)y0 < (unsigned)HH);
    const bool vy1 = ((unsigned)y1 < (unsigned)HH);
    const bool vx0 = ((unsigned)x0 < (unsigned)WW);
    const bool vx1 = ((unsigned)x1 < (unsigned)WW);
    w00 = (vy0 && vx0) ? (1.f - ly) * (1.f - lx) : 0.f;
    w01 = (vy0 && vx1) ? (1.f - ly) * lx         : 0.f;
    w10 = (vy1 && vx0) ? ly * (1.f - lx)         : 0.f;
    w11 = (vy1 && vx1) ? ly * lx                 : 0.f;
    const int cy0 = min(max(y0, 0), HH - 1);
    const int cy1 = min(max(y1, 0), HH - 1);
    const int cx0 = min(max(x0, 0), WW - 1);
    const int cx1 = min(max(x1, 0), WW - 1);
    o00 = (unsigned)((((cy0 << 6) + cx0) << 8) + extra);
    o01 = (unsigned)((((cy0 << 6) + cx1) << 8) + extra);
    o10 = (unsigned)((((cy1 << 6) + cx0) << 8) + extra);
    o11 = (unsigned)((((cy1 << 6) + cx1) << 8) + extra);
}

// bilinear blend of 4 corner uint4s -> bf16x8 A-fragment
__device__ __forceinline__ bf16x8 blend4(const uint4& a00, const uint4& a01,
                                         const uint4& a10, const uint4& a11,
                                         float w00, float w01, float w10, float w11) {
    const unsigned* u00 = reinterpret_cast<const unsigned*>(&a00);
    const unsigned* u01 = reinterpret_cast<const unsigned*>(&a01);
    const unsigned* u10 = reinterpret_cast<const unsigned*>(&a10);
    const unsigned* u11 = reinterpret_cast<const unsigned*>(&a11);
    unsigned afu[4];
#pragma unroll
    for (int j = 0; j < 4; ++j) {
        const float rl = w00 * bflo(u00[j]) + w01 * bflo(u01[j])
                       + w10 * bflo(u10[j]) + w11 * bflo(u11[j]);
        const float rh = w00 * bfhi(u00[j]) + w01 * bfhi(u01[j])
                       + w10 * bfhi(u10[j]) + w11 * bfhi(u11[j]);
        afu[j] = pack2bf(rl, rh);
    }
    bf16x8 afrag;
    __builtin_memcpy(&afrag, afu, 16);
    return afrag;
}

// ---------------- main: fused DCN MFMA, 4-way K-split, 18-phase pipeline ----------------
__global__ __launch_bounds__(512, 6)
void dcn_mfma_kernel(const unsigned short* __restrict__ xt,
                     const unsigned short* __restrict__ wpk,
                     const float* __restrict__ offset,
                     const float* __restrict__ bias,
                     float* __restrict__ out) {
    // LDS: [0,3456) records; [3584, 3584+2*16384) B double buffer; epilogue overlays B.
    __shared__ __align__(16) char smem[3584 + 2 * 16384];
    float2* sLL = reinterpret_cast<float2*>(smem);            // [288]
    short2* sYX = reinterpret_cast<short2*>(smem + 2304);     // [288]
    char*   Bb  = smem + 3584;                                // [2][16384]

    const int t = threadIdx.x;
    // XCD-contiguous swizzle: grid=1024, XCD k owns nid in [k*128,(k+1)*128) = one full
    // b-plane (xt 1 MiB + wpk 288 KiB -> fits the XCD's 4 MiB L2).
    const int bid0 = blockIdx.x;
    const int nid  = ((bid0 & 7) << 7) | (bid0 >> 3);
    const int b    = nid >> 7;
    const int ho   = (nid >> 1) & 63;
    const int wo0  = (nid & 1) << 5;

    const int lane = t & 63;
    const int wave = t >> 6;          // 0..7
    const int mt   = wave & 1;        // 16-wo m-tile within the 32-wo block
    const int kgrp = wave >> 1;       // c0q 0..3 (channel chunk of 32)
    const int lm   = lane & 15;
    const int quad = lane >> 4;
    const int lane16 = lane * 16;
    const int extra = (kgrp << 6) + (quad << 4);   // byte offset inside 256B pixel record
    const char* xb = (const char*)(xt + (size_t)b * HH * WW * CC);
    const char* wb = (const char*)wpk;

    // ---- sampling records: 9 taps x 32 wo ----
    if (t < KTAPS * 32) {
        const int k  = t >> 5;
        const int wo = wo0 + (t & 31);
        const int ki = k / 3;
        const int kj = k - ki * 3;
        const float dy = offset[(((size_t)b * 18 + 2 * k    ) * 64 + ho) * 64 + wo];
        const float dx = offset[(((size_t)b * 18 + 2 * k + 1) * 64 + ho) * 64 + wo];
        const float py = (float)(ho - 1 + ki) + dy;
        const float px = (float)(wo - 1 + kj) + dx;
        const float y0f = floorf(py);
        const float x0f = floorf(px);
        sLL[t] = make_float2(py - y0f, px - x0f);
        sYX[t] = make_short2((short)(int)y0f, (short)(int)x0f);
    }

    // ---- stage phase 0 (tap0, nh0: 16KB) into buffer 0 ----
    {
        const char* src = wb + wave * 2048 + lane16;
        char* dst = Bb + wave * 2048;               // wave-uniform base
        gload_lds16(src, dst);
        gload_lds16(src + 1024, dst + 1024);
    }
    __syncthreads();   // records visible + stage(0) drained

    f32x4 acc[8];
#pragma unroll
    for (int nt = 0; nt < 8; ++nt) acc[nt] = (f32x4){0.f, 0.f, 0.f, 0.f};

    // prologue A: decode tap 0, issue its 4 corner gathers
    unsigned o00, o01, o10, o11;
    float w00, w01, w10, w11;
    decode_tap(sLL, sYX, (mt << 4) + lm, extra, o00, o01, o10, o11, w00, w01, w10, w11);
    uint4 a00 = *reinterpret_cast<const uint4*>(xb + o00);
    uint4 a01 = *reinterpret_cast<const uint4*>(xb + o01);
    uint4 a10 = *reinterpret_cast<const uint4*>(xb + o10);
    uint4 a11 = *reinterpret_cast<const uint4*>(xb + o11);

    for (int tap = 0; tap < KTAPS; ++tap) {
        // ======== phase A (nh=0): reads buf0, stages phase 2*tap+1 -> buf1 ========
        {
            const char* src = wb + ((size_t)((tap << 1) + 1) << 14) + wave * 2048 + lane16;
            char* dst = Bb + 16384 + wave * 2048;
            gload_lds16(src, dst);
            gload_lds16(src + 1024, dst + 1024);
        }
        // blend current tap's A (corners prefetched a full tap ago)
        const bf16x8 afrag = blend4(a00, a01, a10, a11, w00, w01, w10, w11);
        // decode tap+1, issue its gathers (reuses a-regs; ~2 phases to cover latency)
        if (tap < KTAPS - 1) {
            decode_tap(sLL, sYX, ((tap + 1) << 5) + (mt << 4) + lm, extra,
                       o00, o01, o10, o11, w00, w01, w10, w11);
            a00 = *reinterpret_cast<const uint4*>(xb + o00);
            a01 = *reinterpret_cast<const uint4*>(xb + o01);
            a10 = *reinterpret_cast<const uint4*>(xb + o10);
            a11 = *reinterpret_cast<const uint4*>(xb + o11);
        }
        {
            const char* brow = Bb + (kgrp << 12) + lane16;
#pragma unroll
            for (int ntl = 0; ntl < 4; ++ntl) {
                bf16x8 bfrag;
                const uint4 bv = *reinterpret_cast<const uint4*>(brow + (ntl << 10));
                __builtin_memcpy(&bfrag, &bv, 16);
                acc[ntl] = __builtin_amdgcn_mfma_f32_16x16x32_bf16(afrag, bfrag, acc[ntl], 0, 0, 0);
            }
        }
        __syncthreads();   // buf0 reads done + stage(->buf1) drained

        // ======== phase B (nh=1): reads buf1, stages phase 2*tap+2 -> buf0 ========
        if (tap < KTAPS - 1) {
            const char* src = wb + ((size_t)((tap + 1) << 1) << 14) + wave * 2048 + lane16;
            char* dst = Bb + wave * 2048;
            gload_lds16(src, dst);
            gload_lds16(src + 1024, dst + 1024);
        }
        {
            const char* brow = Bb + 16384 + (kgrp << 12) + lane16;
#pragma unroll
            for (int ntl = 0; ntl < 4; ++ntl) {
                bf16x8 bfrag;
                const uint4 bv = *reinterpret_cast<const uint4*>(brow + (ntl << 10));
                __builtin_memcpy(&bfrag, &bv, 16);
                acc[4 + ntl] = __builtin_amdgcn_mfma_f32_16x16x32_bf16(afrag, bfrag, acc[4 + ntl], 0, 0, 0);
            }
        }
        __syncthreads();   // buf1 reads done + stage(->buf0) drained
    }

    // ---- epilogue: 2-round 4-way K-reduction in LDS + direct stores ----
    // B buffers dead (last barrier passed). scr = 32KB overlay.
    char* scr = Bb;
    // round 1: kgrp 1 and 3 write partials (4 waves x 8KB = 32KB)
    if (kgrp & 1) {
        char* w = scr + ((((kgrp >> 1) << 1) + mt) << 13) + lane16;   // slot (kgrp>>1, mt)
#pragma unroll
        for (int nt = 0; nt < 8; ++nt)
            *reinterpret_cast<f32x4*>(w + (nt << 10)) = acc[nt];
    }
    __syncthreads();
    // kgrp0 += kgrp1's slot; kgrp2 += kgrp3's slot
    if (!(kgrp & 1)) {
        const char* r = scr + ((((kgrp >> 1) << 1) + mt) << 13) + lane16;
#pragma unroll
        for (int nt = 0; nt < 8; ++nt) {
            const f32x4 p = *reinterpret_cast<const f32x4*>(r + (nt << 10));
            acc[nt] += p;
        }
    }
    __syncthreads();
    // round 2: kgrp2 writes its sums (2 waves x 8KB)
    if (kgrp == 2) {
        char* w = scr + ((size_t)mt << 13) + lane16;
#pragma unroll
        for (int nt = 0; nt < 8; ++nt)
            *reinterpret_cast<f32x4*>(w + (nt << 10)) = acc[nt];
    }
    __syncthreads();
    if (kgrp == 0) {
        const char* r = scr + ((size_t)mt << 13) + lane16;
#pragma unroll
        for (int nt = 0; nt < 8; ++nt) {
            const f32x4 p = *reinterpret_cast<const f32x4*>(r + (nt << 10));
            const f32x4 s = acc[nt] + p;
            const int o = (nt << 4) + lm;
            const float bv = bias[o];
            float* op = out + (((size_t)(b * OO + o) * HH + ho) << 6)
                      + wo0 + (mt << 4) + (quad << 2);
            *reinterpret_cast<float4*>(op) =
                make_float4(s[0] + bv, s[1] + bv, s[2] + bv, s[3] + bv);
        }
    }
}

extern "C" void kernel_launch(void* const* d_in, const int* in_sizes, int n_in,
                              void* d_out, int out_size, void* d_ws, size_t ws_size,
                              hipStream_t stream) {
    const float* x      = (const float*)d_in[0];
    const float* offset = (const float*)d_in[1];
    const float* wgt    = (const float*)d_in[2];
    const float* bias   = (const float*)d_in[3];
    float* out = (float*)d_out;

    unsigned short* xt  = (unsigned short*)d_ws;                  // 8 MiB
    unsigned short* wpk = xt + (size_t)BB * HH * WW * CC;         // +288 KiB

    hipLaunchKernelGGL(prep_kernel, dim3(512 + 72), dim3(256), 0, stream, x, wgt, xt, wpk);
    hipLaunchKernelGGL(dcn_mfma_kernel, dim3(2 * BB * HH), dim3(512), 0, stream,
                       xt, wpk, offset, bias, out);
}

// Round 6
// 119.456 us; speedup vs baseline: 1.1036x; 1.1036x over previous
//
#include <hip/hip_runtime.h>

// DCNv1 forward on MI355X, bf16 MFMA, round 9: round-4 base + counted-vmcnt raw
// barriers (T4) + setprio around MFMA clusters (T5).
// B=8, C=128, H=W=64, O=128, 3x3, pad=1 -> Ho=Wo=64.
//
// prep_kernel: blocks 0..511: x[B][C][H][W] f32 -> xt[B][H][W][C] bf16
//              blocks 512..583: wgt -> wpk in MFMA B-fragment order.
// dcn_mfma_kernel: grid 512=(b,ho) XCD-swizzled. 512 thr = 8 waves
//   (4 mt x 2 grp/c0q-pair). Per tap: stage next tap's 32KB wpk slice to LDS
//   (4 gload_lds16/wave, issued FIRST), 2 cq phases of {8 ds_read_b128 B-frags,
//   4 A-corner gathers (prefetch), blend, 8 MFMA in setprio(1)}. Tap boundary:
//   s_waitcnt vmcnt(4) (stages drained, next-tap gathers STAY IN FLIGHT) +
//   sched_barrier + raw s_barrier -- no full vmcnt(0) drain (the round-4 cost).
//   Epilogue unchanged: LDS K-reduction + 64B-contiguous stores.

#define BB 8
#define CC 128
#define HH 64
#define WW 64
#define OO 128
#define KTAPS 9

typedef __attribute__((ext_vector_type(8))) short bf16x8;
typedef __attribute__((ext_vector_type(4))) float f32x4;

__device__ __forceinline__ unsigned short f2bf(float f) {
    unsigned u = __float_as_uint(f);
    u += 0x7FFFu + ((u >> 16) & 1u);   // RNE
    return (unsigned short)(u >> 16);
}
#if __has_builtin(__builtin_amdgcn_cvt_pk_bf16_f32)
typedef __attribute__((ext_vector_type(2))) __bf16 bf16x2_t;
__device__ __forceinline__ unsigned pack2bf(float lo, float hi) {
    bf16x2_t v = __builtin_amdgcn_cvt_pk_bf16_f32(lo, hi);
    unsigned r;
    __builtin_memcpy(&r, &v, 4);
    return r;
}
#else
__device__ __forceinline__ unsigned pack2bf(float lo, float hi) {
    return (unsigned)f2bf(lo) | ((unsigned)f2bf(hi) << 16);
}
#endif
__device__ __forceinline__ float bflo(unsigned p) { return __uint_as_float(p << 16); }
__device__ __forceinline__ float bfhi(unsigned p) { return __uint_as_float(p & 0xFFFF0000u); }

// async global->LDS 16B/lane copy; pointers laundered through uintptr_t.
__device__ __forceinline__ void gload_lds16(const void* g, void* l) {
#if __has_builtin(__builtin_amdgcn_global_load_lds)
    auto* lp = reinterpret_cast<__attribute__((address_space(3))) unsigned*>(
        reinterpret_cast<uintptr_t>(l));
    auto* gp = reinterpret_cast<const __attribute__((address_space(1))) unsigned*>(
        reinterpret_cast<uintptr_t>(g));
    __builtin_amdgcn_global_load_lds(gp, lp, 16, 0, 0);
#else
    const int lane = threadIdx.x & 63;
    *reinterpret_cast<uint4*>(reinterpret_cast<char*>(l) + lane * 16) =
        *reinterpret_cast<const uint4*>(reinterpret_cast<const char*>(g) + lane * 16);
#endif
}

// ---------------- prep: transpose x + pack weights (one launch) ----------------
__global__ __launch_bounds__(256)
void prep_kernel(const float* __restrict__ x, const float* __restrict__ wgt,
                 unsigned short* __restrict__ xt, unsigned short* __restrict__ wpk) {
    const int t = threadIdx.x;
    if (blockIdx.x < 512) {
        // ---- x[B][C][H][W] f32 -> xt[B][H][W][C] bf16 ----
        __shared__ float tile[WW * 132];
        const int b = blockIdx.x >> 6;
        const int h = blockIdx.x & 63;
        const float* src = x + ((size_t)b * CC * HH + h) * WW;
        {
            const int wq = t & 15;
            const int cb = t >> 4;
#pragma unroll
            for (int it = 0; it < 8; ++it) {
                const int c = it * 16 + cb;
                const float4 v = *reinterpret_cast<const float4*>(src + (size_t)c * (HH * WW) + wq * 4);
                tile[(wq * 4 + 0) * 132 + c] = v.x;
                tile[(wq * 4 + 1) * 132 + c] = v.y;
                tile[(wq * 4 + 2) * 132 + c] = v.z;
                tile[(wq * 4 + 3) * 132 + c] = v.w;
            }
        }
        __syncthreads();
        unsigned short* dst = xt + ((size_t)b * HH + h) * WW * CC;
        {
            const int cg = t & 15;
            const int wb = t >> 4;
#pragma unroll
            for (int it = 0; it < 4; ++it) {
                const int w = it * 16 + wb;
                const float* tp = &tile[w * 132 + cg * 8];
                uint4 p;
                p.x = pack2bf(tp[0], tp[1]);
                p.y = pack2bf(tp[2], tp[3]);
                p.z = pack2bf(tp[4], tp[5]);
                p.w = pack2bf(tp[6], tp[7]);
                *reinterpret_cast<uint4*>(&dst[(size_t)w * CC + cg * 8]) = p;
            }
        }
    } else {
        // ---- wgt[O][C][3][3] f32 -> wpk fragment-ordered bf16 ----
        const int id   = (blockIdx.x - 512) * 256 + t;   // 0..18431
        const int lane = id & 63;
        const int frag = id >> 6;                        // (tap*4 + c0q)*8 + nt
        const int nt   = frag & 7;
        const int c0q  = (frag >> 3) & 3;
        const int tap  = frag >> 5;
        const int o    = (nt << 4) + (lane & 15);
        const int c    = (c0q << 5) + ((lane >> 4) << 3);
        const float* s = wgt + ((size_t)o * CC + c) * KTAPS + tap;
        unsigned u[4];
#pragma unroll
        for (int j = 0; j < 4; ++j)
            u[j] = pack2bf(s[(2 * j) * KTAPS], s[(2 * j + 1) * KTAPS]);
        *reinterpret_cast<uint4*>(wpk + (size_t)frag * 512 + lane * 8) =
            make_uint4(u[0], u[1], u[2], u[3]);
    }
}

// decode one sampling record -> 4 corner byte-offsets + 4 bilinear weights.
__device__ __forceinline__ void decode_tap(const float2* __restrict__ sLL,
                                           const short2* __restrict__ sYX,
                                           int rec, int extra,
                                           unsigned& o00, unsigned& o01,
                                           unsigned& o10, unsigned& o11,
                                           float& w00, float& w01,
                                           float& w10, float& w11) {
    const float2 ll = sLL[rec];
    const short2 yx = sYX[rec];
    const int y0 = yx.x, x0 = yx.y;
    const int y1 = y0 + 1, x1 = x0 + 1;
    const float ly = ll.x, lx = ll.y;
    const bool vy0 = ((unsigned)y0 < (unsigned)HH);
    const bool vy1 = ((unsigned)y1 < (unsigned)HH);
    const bool vx0 = ((unsigned)x0 < (unsigned)WW);
    const bool vx1 = ((unsigned)x1 < (unsigned)WW);
    w00 = (vy0 && vx0) ? (1.f - ly) * (1.f - lx) : 0.f;
    w01 = (vy0 && vx1) ? (1.f - ly) * lx         : 0.f;
    w10 = (vy1 && vx0) ? ly * (1.f - lx)         : 0.f;
    w11 = (vy1 && vx1) ? ly * lx                 : 0.f;
    const int cy0 = min(max(y0, 0), HH - 1);
    const int cy1 = min(max(y1, 0), HH - 1);
    const int cx0 = min(max(x0, 0), WW - 1);
    const int cx1 = min(max(x1, 0), WW - 1);
    o00 = (unsigned)((((cy0 << 6) + cx0) << 8) + extra);
    o01 = (unsigned)((((cy0 << 6) + cx1) << 8) + extra);
    o10 = (unsigned)((((cy1 << 6) + cx0) << 8) + extra);
    o11 = (unsigned)((((cy1 << 6) + cx1) << 8) + extra);
}

// ---------------- main: fused DCN MFMA, K-split waves + LDS-staged B ----------------
__global__ __launch_bounds__(512, 4)
void dcn_mfma_kernel(const unsigned short* __restrict__ xt,
                     const unsigned short* __restrict__ wpk,
                     const float* __restrict__ offset,
                     const float* __restrict__ bias,
                     float* __restrict__ out) {
    // LDS map (bytes): [0,6912)   sampling records (live through K-loop)
    //                  [6912, 6912+2*32768) B-slice double buffer
    //                  epilogue scratch (40960 B) overlays B buffers after last barrier
    __shared__ __align__(16) char smem[6912 + 2 * 32768];
    float2* sLL = reinterpret_cast<float2*>(smem);            // [576] (ly,lx)
    short2* sYX = reinterpret_cast<short2*>(smem + 4608);     // [576] (y0,x0)
    char*   Bb  = smem + 6912;                                // [2][32768]

    const int t = threadIdx.x;
    // XCD-contiguous swizzle: grid=512, XCD k gets nid in [k*64,(k+1)*64) = one full
    // b-plane (xt 1 MiB + wpk 288 KiB + offsets -> fits the XCD's 4 MiB L2).
    const int bid0 = blockIdx.x;
    const int nid  = ((bid0 & 7) << 6) | (bid0 >> 3);
    const int b    = nid >> 6;
    const int ho   = nid & 63;

    const int lane = t & 63;
    const int wave = t >> 6;          // 0..7
    const int mt   = wave & 3;        // m-tile (16 wo)
    const int grp  = wave >> 2;       // c0q group: {0,1} or {2,3}
    const int lm   = lane & 15;
    const int quad = lane >> 4;
    const int lane16 = lane * 16;
    const int extra = (grp << 7) + (quad << 4);   // byte offset inside 256B record row
    const char* xb = (const char*)(xt + (size_t)b * HH * WW * CC);
    const char* wb = (const char*)wpk;
    const int fb_grp = grp << 1;      // c0q = fb_grp + cq

    // ---- sampling records: 9 taps x 64 wo ----
    for (int s = t; s < KTAPS * 64; s += 512) {
        const int k  = s >> 6;
        const int wo = s & 63;
        const int ki = k / 3;
        const int kj = k - ki * 3;
        const float dy = offset[(((size_t)b * 18 + 2 * k    ) * 64 + ho) * 64 + wo];
        const float dx = offset[(((size_t)b * 18 + 2 * k + 1) * 64 + ho) * 64 + wo];
        const float py = (float)(ho - 1 + ki) + dy;
        const float px = (float)(wo - 1 + kj) + dx;
        const float y0f = floorf(py);
        const float x0f = floorf(px);
        sLL[s] = make_float2(py - y0f, px - x0f);
        sYX[s] = make_short2((short)(int)y0f, (short)(int)x0f);
    }

    // ---- stage tap 0's B slice into buffer 0 (wave w copies bytes [w*4K, w*4K+4K)) ----
    {
        const char* src = wb + wave * 4096 + lane16;
        char* dst = Bb + wave * 4096;           // wave-uniform base
#pragma unroll
        for (int j = 0; j < 4; ++j)
            gload_lds16(src + j * 1024, dst + j * 1024);
    }
    __syncthreads();   // full drain: records visible + stage(0) landed

    f32x4 acc[8];
#pragma unroll
    for (int nt = 0; nt < 8; ++nt) acc[nt] = (f32x4){0.f, 0.f, 0.f, 0.f};

    // prologue: decode tap 0, issue its cq=0 corner loads
    unsigned o00, o01, o10, o11;
    float w00, w01, w10, w11;
    decode_tap(sLL, sYX, (mt << 4) + lm, extra, o00, o01, o10, o11, w00, w01, w10, w11);
    uint4 a00 = *reinterpret_cast<const uint4*>(xb + o00);
    uint4 a01 = *reinterpret_cast<const uint4*>(xb + o01);
    uint4 a10 = *reinterpret_cast<const uint4*>(xb + o10);
    uint4 a11 = *reinterpret_cast<const uint4*>(xb + o11);

    int cur = 0;
    for (int tap = 0; tap < KTAPS; ++tap) {
        // stage next tap's B slice into the other buffer. Issued FIRST so these are
        // the OLDEST outstanding vmem ops of this iteration: the tap-end
        // s_waitcnt vmcnt(4) retires them while the (newer) A-gathers remain in flight.
        if (tap < KTAPS - 1) {
            const char* src = wb + (tap + 1) * 32768 + wave * 4096 + lane16;
            char* dst = Bb + ((cur ^ 1) << 15) + wave * 4096;
#pragma unroll
            for (int j = 0; j < 4; ++j)
                gload_lds16(src + j * 1024, dst + j * 1024);
        }

        const char* bslice = Bb + (cur << 15);
#pragma unroll
        for (int cq = 0; cq < 2; ++cq) {
            // B-frags from LDS (contiguous 1KB per wave per frag -> conflict-free)
            uint4 bfr[8];
            const char* brow = bslice + (((fb_grp + cq) << 13) + lane16);
#pragma unroll
            for (int nt = 0; nt < 8; ++nt)
                bfr[nt] = *reinterpret_cast<const uint4*>(brow + (nt << 10));

            // prefetch next iteration's A corners (double-buffered ACROSS taps)
            uint4 n00, n01, n10, n11;
            unsigned no00 = 0, no01 = 0, no10 = 0, no11 = 0;
            float nw00 = 0.f, nw01 = 0.f, nw10 = 0.f, nw11 = 0.f;
            if (cq == 0) {
                n00 = *reinterpret_cast<const uint4*>(xb + o00 + 64);
                n01 = *reinterpret_cast<const uint4*>(xb + o01 + 64);
                n10 = *reinterpret_cast<const uint4*>(xb + o10 + 64);
                n11 = *reinterpret_cast<const uint4*>(xb + o11 + 64);
            } else if (tap < KTAPS - 1) {
                decode_tap(sLL, sYX, ((tap + 1) << 6) + (mt << 4) + lm, extra,
                           no00, no01, no10, no11, nw00, nw01, nw10, nw11);
                n00 = *reinterpret_cast<const uint4*>(xb + no00);
                n01 = *reinterpret_cast<const uint4*>(xb + no01);
                n10 = *reinterpret_cast<const uint4*>(xb + no10);
                n11 = *reinterpret_cast<const uint4*>(xb + no11);
            }

            // bilinear blend -> bf16 A-frag (uses CURRENT tap's weights)
            const unsigned* u00 = reinterpret_cast<const unsigned*>(&a00);
            const unsigned* u01 = reinterpret_cast<const unsigned*>(&a01);
            const unsigned* u10 = reinterpret_cast<const unsigned*>(&a10);
            const unsigned* u11 = reinterpret_cast<const unsigned*>(&a11);
            unsigned afu[4];
#pragma unroll
            for (int j = 0; j < 4; ++j) {
                const float rl = w00 * bflo(u00[j]) + w01 * bflo(u01[j])
                               + w10 * bflo(u10[j]) + w11 * bflo(u11[j]);
                const float rh = w00 * bfhi(u00[j]) + w01 * bfhi(u01[j])
                               + w10 * bfhi(u10[j]) + w11 * bfhi(u11[j]);
                afu[j] = pack2bf(rl, rh);
            }
            bf16x8 afrag;
            __builtin_memcpy(&afrag, afu, 16);
            __builtin_amdgcn_s_setprio(1);
#pragma unroll
            for (int nt = 0; nt < 8; ++nt) {
                bf16x8 bfrag;
                __builtin_memcpy(&bfrag, &bfr[nt], 16);
                acc[nt] = __builtin_amdgcn_mfma_f32_16x16x32_bf16(afrag, bfrag, acc[nt], 0, 0, 0);
            }
            __builtin_amdgcn_s_setprio(0);

            // rotate the A double buffer
            if (cq == 0) {
                a00 = n00; a01 = n01; a10 = n10; a11 = n11;
            } else if (tap < KTAPS - 1) {
                a00 = n00; a01 = n01; a10 = n10; a11 = n11;
                o00 = no00; o01 = no01; o10 = no10; o11 = no11;
                w00 = nw00; w01 = nw01; w10 = nw10; w11 = nw11;
            }
        }

        // counted-vmcnt tap boundary (T4): wait only until <=4 vmem ops remain.
        // Oldest-first retirement => the 4 stage ops (issued first) are done; the
        // 4 next-tap A-gathers (issued last) may stay in flight across the barrier.
        // ds_reads of buf[cur] were consumed by MFMA (compiler lgkmcnt) pre-barrier.
        asm volatile("s_waitcnt vmcnt(4)" ::: "memory");
        __builtin_amdgcn_sched_barrier(0);
        __builtin_amdgcn_s_barrier();
        cur ^= 1;
    }

    // ---- epilogue: pairwise K-reduction + LDS transpose -> 64B-contiguous stores ----
    __syncthreads();   // full drain; B buffers dead -> overlay scratch
    float* scrA = reinterpret_cast<float*>(Bb);
    float* scrM = scrA + mt * (128 * 20);
    if (grp == 0) {
#pragma unroll
        for (int nt = 0; nt < 8; ++nt) {
            const int o_l = (nt << 4) + lm;
            *reinterpret_cast<float4*>(&scrM[o_l * 20 + (quad << 2)]) =
                make_float4(acc[nt][0], acc[nt][1], acc[nt][2], acc[nt][3]);
        }
    }
    __syncthreads();
    if (grp == 1) {
#pragma unroll
        for (int nt = 0; nt < 8; ++nt) {
            const int o_l = (nt << 4) + lm;
            float4* p = reinterpret_cast<float4*>(&scrM[o_l * 20 + (quad << 2)]);
            float4 f = *p;
            f.x += acc[nt][0]; f.y += acc[nt][1];
            f.z += acc[nt][2]; f.w += acc[nt][3];
            *p = f;
        }
    }
    __syncthreads();
    {
        const int o = (grp << 6) + lane;          // 8 waves x 64 lanes cover 4 mt x 128 o
        const float bv = bias[o];
        float* op = out + (((size_t)(b * OO + o) * HH + ho) << 6) + (mt << 4);
        const float* sr = scrM + o * 20;
#pragma unroll
        for (int j = 0; j < 4; ++j) {
            const float4 f = *reinterpret_cast<const float4*>(sr + j * 4);
            *reinterpret_cast<float4*>(op + j * 4) =
                make_float4(f.x + bv, f.y + bv, f.z + bv, f.w + bv);
        }
    }
}

extern "C" void kernel_launch(void* const* d_in, const int* in_sizes, int n_in,
                              void* d_out, int out_size, void* d_ws, size_t ws_size,
                              hipStream_t stream) {
    const float* x      = (const float*)d_in[0];
    const float* offset = (const float*)d_in[1];
    const float* wgt    = (const float*)d_in[2];
    const float* bias   = (const float*)d_in[3];
    float* out = (float*)d_out;

    unsigned short* xt  = (unsigned short*)d_ws;                  // 8 MiB
    unsigned short* wpk = xt + (size_t)BB * HH * WW * CC;         // +288 KiB

    hipLaunchKernelGGL(prep_kernel, dim3(512 + 72), dim3(256), 0, stream, x, wgt, xt, wpk);
    hipLaunchKernelGGL(dcn_mfma_kernel, dim3(BB * HH), dim3(512), 0, stream,
                       xt, wpk, offset, bias, out);
}